// Round 12
// baseline (642.505 us; speedup 1.0000x reference)
//
#include <hip/hip_runtime.h>

// GPR-GNN: out = b_fc + sum_k temp[k] * A_hat^k (MLP(x) @ W_fc)
// Trick 1: project features to scalar BEFORE propagation -> 1 float/node.
// Trick 2: per-edge GLOBAL atomics cost ~35B memory-side RMW (R2/R3) ->
//          per-edge atomics are LDS-only.
// Trick 3: u-space propagation u_k = D^{-1/2} z_k -> per-edge work = one add.
// Trick 4: CSR build = two-level counting sort (98 buckets of 1024 targets;
//          pass-2 sorts each bucket's edges by source macro-tile).
// Trick 8 (R12): hop = split-source LDS-tiled SpMV. Grid 98 chunks x 7 tiles
//          = 686 independent blocks (R10's 196-block serial-phase cliff fixed).
//          Block: stage 56KB source tile coalesced -> LDS, edges = LDS read +
//          LDS atomic into 4KB acc, write partial coalesced. LAST block per
//          chunk (ACQ_REL agent atomic: release wbL2 publishes partials across
//          non-coherent XCD L2s) reduces 7 partials + self-loop -> ucur/out.
//          Replaces ~420MB/hop random 128B-line gather traffic (20us floor,
//          R7/R9/R11) with 38MB sequential staging.
// ANTI-LESSON (R8): cooperative grid.sync ~125us each on 8-XCD MI355X. Never.
// ANTI-LESSON (R9): MLP fused into scatter adds ~20us serial wave chains.

#define TPB  256
#define TSC  512             // scatter block threads
#define SBSH 10              // 1024 targets per bucket
#define CAP1 37376           // bucket capacity (mean ~32650, ~16 sigma)
#define EPT  8               // edges per thread in pass 1
#define CH   (TSC * EPT)     // 4096 edges per scatter block
#define TILE 14336           // source macro-tile (56KB LDS)
#define NSUB 8               // contention-spreading sub-bins in k_sub sort

// ---- MLP (thread per node, register-blocked) + cursor/counter zeroing ----
__global__ void k_mlp(const float* __restrict__ x, const float* __restrict__ W1,
                      const float* __restrict__ b1, const float* __restrict__ W2,
                      const float* __restrict__ b2, const float* __restrict__ Wfc,
                      float* __restrict__ zarr, int* __restrict__ bcursor,
                      int* __restrict__ cnt, int ncnt, int n) {
    int i = blockIdx.x * blockDim.x + threadIdx.x;
    if (i < 128) bcursor[i] = 0;
    if (i < ncnt) cnt[i] = 0;
    if (i >= n) return;
    float xv = x[i];
    float h1[32];
#pragma unroll
    for (int j = 0; j < 32; j++)
        h1[j] = fmaxf(fmaf(xv, W1[j], b1[j]), 0.f);
    float z = 0.f;
#pragma unroll
    for (int fc = 0; fc < 4; fc++) {
        float acc[16];
#pragma unroll
        for (int f = 0; f < 16; f++) acc[f] = b2[fc * 16 + f];
#pragma unroll
        for (int j = 0; j < 32; j++) {
            float h = h1[j];
#pragma unroll
            for (int f = 0; f < 16; f++)
                acc[f] = fmaf(h, W2[j * 64 + fc * 16 + f], acc[f]);
        }
#pragma unroll
        for (int f = 0; f < 16; f++)
            z = fmaf(fmaxf(acc[f], 0.f), Wfc[fc * 16 + f], z);
    }
    zarr[i] = z;
}

// ---- Pass 1: bucket edges into 98 buckets, packed (row<<10)|tgt10 ----
__global__ void __launch_bounds__(TSC)
k_scatter(const int* __restrict__ erow, const int* __restrict__ ecol,
          int* __restrict__ bcursor, unsigned int* __restrict__ ebuf1,
          int e, int nsb) {
    __shared__ int hist[128];
    __shared__ int base[128];
    int t = threadIdx.x;
    int s = blockIdx.x * CH;
    int r[EPT], c[EPT];

    if (t < 128) hist[t] = 0;
    __syncthreads();
#pragma unroll
    for (int j = 0; j < EPT; j++) {
        int i = s + j * TSC + t;
        bool ok = (i < e);
        c[j] = ok ? ecol[i] : -1;
        r[j] = ok ? erow[i] : 0;
        if (ok) atomicAdd(&hist[c[j] >> SBSH], 1);
    }
    __syncthreads();
    if (t < nsb) {
        int cc = hist[t];
        base[t] = cc ? atomicAdd(&bcursor[t], cc) : 0;
        hist[t] = 0;
    }
    __syncthreads();
#pragma unroll
    for (int j = 0; j < EPT; j++) {
        if (c[j] >= 0) {
            int b = c[j] >> SBSH;
            int pos = base[b] + atomicAdd(&hist[b], 1);
            if (pos < CAP1)
                ebuf1[(size_t)b * CAP1 + pos] =
                    ((unsigned int)r[j] << SBSH) | (unsigned int)(c[j] & 1023);
        }
    }
}

// ---- Pass 2: per bucket, sort edges by source macro-tile into csr as
// (src_local<<10)|tgt10; emit sofs bin ranges, norms, u0/out init ----
__global__ void __launch_bounds__(1024)
k_sub(const int* __restrict__ bcursor, const unsigned int* __restrict__ ebuf1,
      unsigned int* __restrict__ csr, int* __restrict__ sofs,
      float2* __restrict__ nrm, const float* __restrict__ zarr,
      const float* __restrict__ temp, const float* __restrict__ bfc,
      float* __restrict__ u0, float* __restrict__ out, int n, int MT) {
    __shared__ int deg[1024];
    __shared__ int binh[64];               // MT*NSUB = 56 bins
    int b = blockIdx.x;
    int t = threadIdx.x;
    int nbin = MT * NSUB;

    deg[t] = 0;
    if (t < nbin) binh[t] = 0;
    __syncthreads();
    int cnt = min(bcursor[b], CAP1);
    size_t g = (size_t)b * CAP1;
    for (int j = t; j < cnt; j += 1024) {
        unsigned int p = ebuf1[g + j];
        int tgt = p & 1023;
        int row = p >> SBSH;
        int bin = (row / TILE) * NSUB + ((row >> 11) & (NSUB - 1));
        atomicAdd(&deg[tgt], 1);
        atomicAdd(&binh[bin], 1);
    }
    __syncthreads();
    if (t == 0) {
        int acc = 0;
        for (int i = 0; i < nbin; i++) { int c = binh[i]; binh[i] = acc; acc += c; }
    }
    __syncthreads();
    // sofs boundaries (absolute csr offsets), MT+1 per bucket
    if (t <= MT)
        sofs[b * (MT + 1) + t] = (int)g + ((t == MT) ? cnt : binh[t * NSUB]);
    int node = (b << SBSH) + t;
    if (node < n) {
        float d = (float)(deg[t] + 1);     // +1 self-loop
        float di = rsqrtf(d);
        nrm[node] = make_float2(di * di, d * di);   // {dinv2, sqrt(d)}
        float z = zarr[node];
        u0[node] = di * z;
        out[node] = fmaf(temp[0], z, bfc[0]);
    }
    __syncthreads();
    // binh now = exclusive cursors
    for (int j = t; j < cnt; j += 1024) {
        unsigned int p = ebuf1[g + j];
        int tgt = p & 1023;
        int row = p >> SBSH;
        int m = row / TILE;
        int bin = m * NSUB + ((row >> 11) & (NSUB - 1));
        int pos = atomicAdd(&binh[bin], 1);
        int srcl = row - m * TILE;
        csr[g + pos] = ((unsigned int)srcl << SBSH) | (unsigned int)tgt;
    }
}

// ---- Hop k: block (chunk c, tile m). Stage tile m (56KB) coalesced into
// LDS, edges -> LDS acc[1024], partial -> zpart[m]. Last block per chunk
// reduces partials + self-loop -> ucur/out. ----
__global__ void __launch_bounds__(512)
k_hop(const int* __restrict__ sofs, const unsigned int* __restrict__ csr,
      const float2* __restrict__ nrm, const float* __restrict__ uprev,
      float* __restrict__ ucur, float* __restrict__ out,
      const float* __restrict__ temp, float* __restrict__ zpart,
      int* __restrict__ cnt, int k, int K, int n, int MT) {
    __shared__ float tile[TILE];           // 56 KB
    __shared__ float acc[1024];            // 4 KB
    __shared__ int lastflag;
    int c = blockIdx.x;
    int m = blockIdx.y;
    int t = threadIdx.x;

    // stage source tile m (coalesced float4)
    const float4* u4 = (const float4*)uprev;
    float4* t4 = (float4*)tile;
#pragma unroll
    for (int q = 0; q < TILE / 2048; q++)
        t4[q * 512 + t] = u4[(size_t)m * (TILE / 4) + q * 512 + t];
    acc[t] = 0.f;
    acc[t + 512] = 0.f;
    __syncthreads();

    int j0 = sofs[c * (MT + 1) + m], j1 = sofs[c * (MT + 1) + m + 1];
    for (int j = j0 + t; j < j1; j += 512) {
        unsigned int p = csr[j];
        atomicAdd(&acc[p & 1023], tile[p >> SBSH]);
    }
    __syncthreads();

    // write partial (coalesced, no atomics)
    size_t zb = (size_t)m * (98 * 1024) + (size_t)c * 1024;
    zpart[zb + t] = acc[t];
    zpart[zb + t + 512] = acc[t + 512];
    __syncthreads();                        // all stores issued & drained

    if (t == 0) {
        // release: publish partials across non-coherent XCD L2s; acquire:
        // invalidate before tail reads other XCDs' partials.
        int prev = __hip_atomic_fetch_add(&cnt[c], 1, __ATOMIC_ACQ_REL,
                                          __HIP_MEMORY_SCOPE_AGENT);
        lastflag = (prev == MT - 1) ? 1 : 0;
    }
    __syncthreads();
    if (!lastflag) return;

    // tail: reduce MT partials for this chunk's 1024 nodes
    for (int i = t; i < 1024; i += 512) {
        int node = (c << SBSH) + i;
        if (node >= n) continue;
        float sum = uprev[node];            // self-loop
        for (int mm = 0; mm < MT; mm++)
            sum += zpart[(size_t)mm * (98 * 1024) + (size_t)c * 1024 + i];
        float2 nv = nrm[node];              // {dinv2, sqrt(d)}
        float u = nv.x * sum;
        if (k < K) ucur[node] = u;
        out[node] = fmaf(temp[k] * nv.y, u, out[node]);
    }
}

static inline size_t align256(size_t v) { return (v + 255) & ~(size_t)255; }

extern "C" void kernel_launch(void* const* d_in, const int* in_sizes, int n_in,
                              void* d_out, int out_size, void* d_ws, size_t ws_size,
                              hipStream_t stream) {
    const float* x    = (const float*)d_in[0];
    const int*   ei   = (const int*)d_in[1];
    const float* W1   = (const float*)d_in[2];
    const float* b1   = (const float*)d_in[3];
    const float* W2   = (const float*)d_in[4];
    const float* b2   = (const float*)d_in[5];
    const float* temp = (const float*)d_in[6];
    const float* Wfc  = (const float*)d_in[7];
    const float* bfc  = (const float*)d_in[8];

    const int n = in_sizes[0];        // 100000 nodes
    const int e = in_sizes[1] / 2;    // 3.2M edges
    const int K = in_sizes[6] - 1;    // 10 hops
    const int nsb = (n + (1 << SBSH) - 1) >> SBSH;   // 98 buckets
    const int MT  = (n + TILE - 1) / TILE;            // 7 source tiles

    const int* erow = ei;             // edge_index[0] = source
    const int* ecol = ei + e;         // edge_index[1] = target

    float* out = (float*)d_out;

    const size_t upad = (size_t)MT * TILE + 64;       // staging reads past n

    // workspace carve
    char* ws = (char*)d_ws;
    int*          bcursor = (int*)ws;          ws += align256((size_t)128 * 4);
    int*          cnt     = (int*)ws;          ws += align256((size_t)K * nsb * 4);
    unsigned int* ebuf1   = (unsigned int*)ws; ws += align256((size_t)nsb * CAP1 * 4);
    unsigned int* csr     = (unsigned int*)ws; ws += align256((size_t)nsb * CAP1 * 4);
    int*          sofs    = (int*)ws;          ws += align256((size_t)nsb * (MT + 1) * 4);
    float2*       nrm     = (float2*)ws;       ws += align256((size_t)n * 8);
    float*        zarr    = (float*)ws;        ws += align256((size_t)n * 4);
    float*        zpart   = (float*)ws;        ws += align256((size_t)MT * nsb * 1024 * 4);
    float*        u0      = (float*)ws;        ws += align256(upad * 4);
    float*        u1      = (float*)ws;        ws += align256(upad * 4);

    const int gM = (n + TPB - 1) / TPB;          // 391 MLP blocks
    const int gS = (e + CH - 1) / CH;            // 782 scatter blocks

    k_mlp<<<gM, TPB, 0, stream>>>(x, W1, b1, W2, b2, Wfc, zarr, bcursor,
                                  cnt, K * nsb, n);
    k_scatter<<<gS, TSC, 0, stream>>>(erow, ecol, bcursor, ebuf1, e, nsb);
    k_sub<<<nsb, 1024, 0, stream>>>(bcursor, ebuf1, csr, sofs, nrm,
                                    zarr, temp, bfc, u0, out, n, MT);

    float* uin = u0;
    float* uout = u1;
    for (int k = 1; k <= K; k++) {
        k_hop<<<dim3(nsb, MT), 512, 0, stream>>>(sofs, csr, nrm, uin, uout, out,
                                                 temp, zpart, cnt + (size_t)(k - 1) * nsb,
                                                 k, K, n, MT);
        float* t2 = uin; uin = uout; uout = t2;
    }
}

// Round 13
// 481.026 us; speedup vs baseline: 1.3357x; 1.3357x over previous
//
#include <hip/hip_runtime.h>

// GPR-GNN: out = b_fc + sum_k temp[k] * A_hat^k (MLP(x) @ W_fc)
// Trick 1: project features to scalar BEFORE propagation -> 1 float/node.
// Trick 2: per-edge GLOBAL atomics cost ~35B memory-side RMW (R2/R3) ->
//          per-edge atomics are LDS-only.
// Trick 3: u-space propagation u_k = D^{-1/2} z_k -> per-edge work = one add.
// Trick 4: CSR build = two-level counting sort (98 buckets of 1024 targets;
//          pass-2 sorts each bucket's edges by 8192-node source tile).
// Trick 9 (R13): hop = fence-free split-source SpMV in TWO kernels.
//          A: 49 chunks x 13 tiles = 637 blocks, stage 32KB tile -> LDS,
//             edges = LDS read + LDS atomic into 8KB acc(2048 tgts), write
//             partial coalesced. NO global atomics, NO fences.
//          B: thread/node reduce of 13 partials + self-loop -> ucur/out.
//          The kernel boundary is the cross-XCD sync (~3us, measured across
//          all multi-kernel rounds).
// ANTI-LESSON (R8): cooperative grid.sync ~125us each on 8-XCD MI355X.
// ANTI-LESSON (R12): in-kernel ACQ_REL agent atomics for cross-block handoff
//          cost us-scale each (L2 wb/inv across XCDs) -> 55us/hop. Never.
// ANTI-LESSON (R9): MLP fused into scatter adds ~20us serial wave chains.

#define TPB  256
#define TSC  512             // scatter block threads
#define SBSH 10              // 1024 targets per build bucket
#define CAP1 37376           // bucket capacity (mean ~32650, ~16 sigma)
#define EPT  8               // edges per thread in pass 1
#define CH   (TSC * EPT)     // 4096 edges per scatter block
#define TILE 8192            // source tile (32KB LDS), power of 2
#define NSUB 8               // contention-spreading sub-bins in k_sub sort
#define NCH  49              // target chunks of 2048 (= 2 buckets)
#define NPAD (NCH * 2048)    // zpart stride (100352)

// ---- MLP (thread per node, register-blocked) + bcursor zeroing ----
__global__ void k_mlp(const float* __restrict__ x, const float* __restrict__ W1,
                      const float* __restrict__ b1, const float* __restrict__ W2,
                      const float* __restrict__ b2, const float* __restrict__ Wfc,
                      float* __restrict__ zarr, int* __restrict__ bcursor, int n) {
    int i = blockIdx.x * blockDim.x + threadIdx.x;
    if (i < 128) bcursor[i] = 0;
    if (i >= n) return;
    float xv = x[i];
    float h1[32];
#pragma unroll
    for (int j = 0; j < 32; j++)
        h1[j] = fmaxf(fmaf(xv, W1[j], b1[j]), 0.f);
    float z = 0.f;
#pragma unroll
    for (int fc = 0; fc < 4; fc++) {
        float acc[16];
#pragma unroll
        for (int f = 0; f < 16; f++) acc[f] = b2[fc * 16 + f];
#pragma unroll
        for (int j = 0; j < 32; j++) {
            float h = h1[j];
#pragma unroll
            for (int f = 0; f < 16; f++)
                acc[f] = fmaf(h, W2[j * 64 + fc * 16 + f], acc[f]);
        }
#pragma unroll
        for (int f = 0; f < 16; f++)
            z = fmaf(fmaxf(acc[f], 0.f), Wfc[fc * 16 + f], z);
    }
    zarr[i] = z;
}

// ---- Pass 1: bucket edges into 98 buckets, packed (row<<10)|tgt10 ----
__global__ void __launch_bounds__(TSC)
k_scatter(const int* __restrict__ erow, const int* __restrict__ ecol,
          int* __restrict__ bcursor, unsigned int* __restrict__ ebuf1,
          int e, int nsb) {
    __shared__ int hist[128];
    __shared__ int base[128];
    int t = threadIdx.x;
    int s = blockIdx.x * CH;
    int r[EPT], c[EPT];

    if (t < 128) hist[t] = 0;
    __syncthreads();
#pragma unroll
    for (int j = 0; j < EPT; j++) {
        int i = s + j * TSC + t;
        bool ok = (i < e);
        c[j] = ok ? ecol[i] : -1;
        r[j] = ok ? erow[i] : 0;
        if (ok) atomicAdd(&hist[c[j] >> SBSH], 1);
    }
    __syncthreads();
    if (t < nsb) {
        int cc = hist[t];
        base[t] = cc ? atomicAdd(&bcursor[t], cc) : 0;
        hist[t] = 0;
    }
    __syncthreads();
#pragma unroll
    for (int j = 0; j < EPT; j++) {
        if (c[j] >= 0) {
            int b = c[j] >> SBSH;
            int pos = base[b] + atomicAdd(&hist[b], 1);
            if (pos < CAP1)
                ebuf1[(size_t)b * CAP1 + pos] =
                    ((unsigned int)r[j] << SBSH) | (unsigned int)(c[j] & 1023);
        }
    }
}

// ---- Pass 2: per bucket, sort edges by 8192-source-tile into csr as
// (src_local<<10)|tgt10; emit sofs bin ranges, norms, u0/out init ----
__global__ void __launch_bounds__(1024)
k_sub(const int* __restrict__ bcursor, const unsigned int* __restrict__ ebuf1,
      unsigned int* __restrict__ csr, int* __restrict__ sofs,
      float2* __restrict__ nrm, const float* __restrict__ zarr,
      const float* __restrict__ temp, const float* __restrict__ bfc,
      float* __restrict__ u0, float* __restrict__ out, int n, int MT) {
    __shared__ int deg[1024];
    __shared__ int binh[128];              // MT*NSUB = 104 bins
    int b = blockIdx.x;
    int t = threadIdx.x;
    int nbin = MT * NSUB;

    deg[t] = 0;
    if (t < nbin) binh[t] = 0;
    __syncthreads();
    int cnt = min(bcursor[b], CAP1);
    size_t g = (size_t)b * CAP1;
    for (int j = t; j < cnt; j += 1024) {
        unsigned int p = ebuf1[g + j];
        int tgt = p & 1023;
        int row = p >> SBSH;
        int bin = (row >> 13) * NSUB + ((row >> 10) & (NSUB - 1));
        atomicAdd(&deg[tgt], 1);
        atomicAdd(&binh[bin], 1);
    }
    __syncthreads();
    if (t == 0) {
        int acc = 0;
        for (int i = 0; i < nbin; i++) { int c = binh[i]; binh[i] = acc; acc += c; }
    }
    __syncthreads();
    // sofs boundaries (absolute csr offsets), MT+1 per bucket
    if (t <= MT)
        sofs[b * (MT + 1) + t] = (int)g + ((t == MT) ? cnt : binh[t * NSUB]);
    int node = (b << SBSH) + t;
    if (node < n) {
        float d = (float)(deg[t] + 1);     // +1 self-loop
        float di = rsqrtf(d);
        nrm[node] = make_float2(di * di, d * di);   // {dinv2, sqrt(d)}
        float z = zarr[node];
        u0[node] = di * z;
        out[node] = fmaf(temp[0], z, bfc[0]);
    }
    __syncthreads();
    // binh now = exclusive cursors
    for (int j = t; j < cnt; j += 1024) {
        unsigned int p = ebuf1[g + j];
        int tgt = p & 1023;
        int row = p >> SBSH;
        int m = row >> 13;
        int bin = m * NSUB + ((row >> 10) & (NSUB - 1));
        int pos = atomicAdd(&binh[bin], 1);
        int srcl = row & (TILE - 1);
        csr[g + pos] = ((unsigned int)srcl << SBSH) | (unsigned int)tgt;
    }
}

// ---- Hop kernel A: block (chunk c, tile m). Stage tile m (32KB) coalesced
// into LDS; edges of buckets {2c,2c+1} at tile m: LDS read + LDS atomicAdd
// into acc[2048]; write partial coalesced. No fences, no global atomics. ----
__global__ void __launch_bounds__(512)
k_spmv(const int* __restrict__ sofs, const unsigned int* __restrict__ csr,
       const float* __restrict__ uprev, float* __restrict__ zpart, int MT) {
    __shared__ float tile[TILE];           // 32 KB
    __shared__ float acc[2048];            // 8 KB
    int c = blockIdx.x;
    int m = blockIdx.y;
    int t = threadIdx.x;

    const float4* u4 = (const float4*)uprev;
    float4* t4 = (float4*)tile;
#pragma unroll
    for (int q = 0; q < TILE / 2048; q++)
        t4[q * 512 + t] = u4[(size_t)m * (TILE / 4) + q * 512 + t];
    acc[t] = 0.f; acc[t + 512] = 0.f; acc[t + 1024] = 0.f; acc[t + 1536] = 0.f;
    __syncthreads();

#pragma unroll
    for (int half = 0; half < 2; half++) {
        int b = 2 * c + half;
        int j0 = sofs[b * (MT + 1) + m], j1 = sofs[b * (MT + 1) + m + 1];
        int aofs = half << 10;
        for (int j = j0 + t; j < j1; j += 512) {
            unsigned int p = csr[j];
            atomicAdd(&acc[aofs + (p & 1023)], tile[p >> SBSH]);
        }
    }
    __syncthreads();

    size_t zb = (size_t)m * NPAD + (size_t)c * 2048;
    zpart[zb + t]        = acc[t];
    zpart[zb + t + 512]  = acc[t + 512];
    zpart[zb + t + 1024] = acc[t + 1024];
    zpart[zb + t + 1536] = acc[t + 1536];
}

// ---- Hop kernel B: thread/node reduce of MT partials + self-loop ----
__global__ void k_reduce(const float* __restrict__ zpart,
                         const float* __restrict__ uprev,
                         const float2* __restrict__ nrm,
                         const float* __restrict__ temp,
                         float* __restrict__ ucur, float* __restrict__ out,
                         int k, int K, int n, int MT) {
    int i = blockIdx.x * blockDim.x + threadIdx.x;
    if (i >= n) return;
    float sum = uprev[i];                  // self-loop
    for (int m = 0; m < MT; m++)
        sum += zpart[(size_t)m * NPAD + i];
    float2 nv = nrm[i];                    // {dinv2, sqrt(d)}
    float u = nv.x * sum;
    if (k < K) ucur[i] = u;
    out[i] = fmaf(temp[k] * nv.y, u, out[i]);
}

static inline size_t align256(size_t v) { return (v + 255) & ~(size_t)255; }

extern "C" void kernel_launch(void* const* d_in, const int* in_sizes, int n_in,
                              void* d_out, int out_size, void* d_ws, size_t ws_size,
                              hipStream_t stream) {
    const float* x    = (const float*)d_in[0];
    const int*   ei   = (const int*)d_in[1];
    const float* W1   = (const float*)d_in[2];
    const float* b1   = (const float*)d_in[3];
    const float* W2   = (const float*)d_in[4];
    const float* b2   = (const float*)d_in[5];
    const float* temp = (const float*)d_in[6];
    const float* Wfc  = (const float*)d_in[7];
    const float* bfc  = (const float*)d_in[8];

    const int n = in_sizes[0];        // 100000 nodes
    const int e = in_sizes[1] / 2;    // 3.2M edges
    const int K = in_sizes[6] - 1;    // 10 hops
    const int nsb = (n + (1 << SBSH) - 1) >> SBSH;   // 98 buckets
    const int MT  = (n + TILE - 1) / TILE;            // 13 source tiles

    const int* erow = ei;             // edge_index[0] = source
    const int* ecol = ei + e;         // edge_index[1] = target

    float* out = (float*)d_out;

    const size_t upad = (size_t)MT * TILE + 64;       // staging reads past n

    // workspace carve
    char* ws = (char*)d_ws;
    int*          bcursor = (int*)ws;          ws += align256((size_t)128 * 4);
    unsigned int* ebuf1   = (unsigned int*)ws; ws += align256((size_t)nsb * CAP1 * 4);
    unsigned int* csr     = (unsigned int*)ws; ws += align256((size_t)nsb * CAP1 * 4);
    int*          sofs    = (int*)ws;          ws += align256((size_t)nsb * (MT + 1) * 4);
    float2*       nrm     = (float2*)ws;       ws += align256((size_t)n * 8);
    float*        zarr    = (float*)ws;        ws += align256((size_t)n * 4);
    float*        zpart   = (float*)ws;        ws += align256((size_t)MT * NPAD * 4);
    float*        u0      = (float*)ws;        ws += align256(upad * 4);
    float*        u1      = (float*)ws;        ws += align256(upad * 4);

    const int gM = (n + TPB - 1) / TPB;          // 391 blocks
    const int gS = (e + CH - 1) / CH;            // 782 scatter blocks

    k_mlp<<<gM, TPB, 0, stream>>>(x, W1, b1, W2, b2, Wfc, zarr, bcursor, n);
    k_scatter<<<gS, TSC, 0, stream>>>(erow, ecol, bcursor, ebuf1, e, nsb);
    k_sub<<<nsb, 1024, 0, stream>>>(bcursor, ebuf1, csr, sofs, nrm,
                                    zarr, temp, bfc, u0, out, n, MT);

    float* uin = u0;
    float* uout = u1;
    for (int k = 1; k <= K; k++) {
        k_spmv<<<dim3(NCH, MT), 512, 0, stream>>>(sofs, csr, uin, zpart, MT);
        k_reduce<<<gM, TPB, 0, stream>>>(zpart, uin, nrm, temp, uout, out,
                                         k, K, n, MT);
        float* t2 = uin; uin = uout; uout = t2;
    }
}

// Round 14
// 357.095 us; speedup vs baseline: 1.7993x; 1.3471x over previous
//
#include <hip/hip_runtime.h>

// GPR-GNN: out = b_fc + sum_k temp[k] * A_hat^k (MLP(x) @ W_fc)
// Trick 1: project features to scalar BEFORE propagation -> 1 float/node.
// Trick 2: per-edge GLOBAL atomics cost ~35B memory-side RMW (R2/R3) ->
//          per-edge atomics are LDS-only.
// Trick 3: u-space propagation u_k = D^{-1/2} z_k -> per-edge work is one
//          unweighted gather+add; CSR is row indices only.
// Trick 4: CSR build = two-level counting sort (98 buckets of 1024 nodes).
// Trick 5: segments padded to x4; pads index dummy slot n (u[n]=0) -> hop does
//          aligned uint4 index loads + 4 independent gathers each, no masking.
// Trick 10 (R14): csr stream (13.6MB/hop, zero reuse) read NONTEMPORAL so it
//          doesn't thrash the 4MB/XCD L2 where the 400KB u-array lives;
//          4 threads/node (2 uint4 + 8 gathers in flight per thread).
// MEASURED: tiled SpMV hops lose 3 ways (R10 serial phases, R12 in-kernel
//          fences ~us each, R13 per-block staging overhead + 2x launches).
//          Plain gather hop ~20us; HBM traffic only ~18MB -> latency/L2 bound.
// ANTI-LESSON (R8): cooperative grid.sync ~125us each on 8-XCD MI355X.
// ANTI-LESSON (R9): MLP fused into scatter adds ~20us serial wave chains.

#define TPB  256
#define TSC  512             // scatter block threads
#define SBSH 10              // 1024 nodes per super-bucket
#define CAP1 37376           // capacity (mean padded ~34200, ~16 sigma; mult of 4)
#define EPT  8               // edges per thread in pass 1
#define CH   (TSC * EPT)     // 4096 edges per scatter block

typedef unsigned int v4u __attribute__((ext_vector_type(4)));

// ---- MLP (thread per node, register-blocked) + bcursor zeroing ----
__global__ void k_mlp(const float* __restrict__ x, const float* __restrict__ W1,
                      const float* __restrict__ b1, const float* __restrict__ W2,
                      const float* __restrict__ b2, const float* __restrict__ Wfc,
                      float* __restrict__ zarr, int* __restrict__ bcursor, int n) {
    int i = blockIdx.x * blockDim.x + threadIdx.x;
    if (i < 128) bcursor[i] = 0;
    if (i >= n) return;
    float xv = x[i];
    float h1[32];
#pragma unroll
    for (int j = 0; j < 32; j++)
        h1[j] = fmaxf(fmaf(xv, W1[j], b1[j]), 0.f);
    float z = 0.f;
#pragma unroll
    for (int fc = 0; fc < 4; fc++) {
        float acc[16];
#pragma unroll
        for (int f = 0; f < 16; f++) acc[f] = b2[fc * 16 + f];
#pragma unroll
        for (int j = 0; j < 32; j++) {
            float h = h1[j];
#pragma unroll
            for (int f = 0; f < 16; f++)
                acc[f] = fmaf(h, W2[j * 64 + fc * 16 + f], acc[f]);
        }
#pragma unroll
        for (int f = 0; f < 16; f++)
            z = fmaf(fmaxf(acc[f], 0.f), Wfc[fc * 16 + f], z);
    }
    zarr[i] = z;
}

// ---- Pass 1: bucket edges into 98 super-buckets, packed (row<<10)|tgt10 ----
__global__ void __launch_bounds__(TSC)
k_scatter(const int* __restrict__ erow, const int* __restrict__ ecol,
          int* __restrict__ bcursor, unsigned int* __restrict__ ebuf1,
          int e, int nsb) {
    __shared__ int hist[128];
    __shared__ int base[128];
    int t = threadIdx.x;
    int s = blockIdx.x * CH;
    int r[EPT], c[EPT];

    if (t < 128) hist[t] = 0;
    __syncthreads();
#pragma unroll
    for (int j = 0; j < EPT; j++) {
        int i = s + j * TSC + t;
        bool ok = (i < e);
        c[j] = ok ? ecol[i] : -1;
        r[j] = ok ? erow[i] : 0;
        if (ok) atomicAdd(&hist[c[j] >> SBSH], 1);
    }
    __syncthreads();
    if (t < nsb) {
        int cc = hist[t];
        base[t] = cc ? atomicAdd(&bcursor[t], cc) : 0;
        hist[t] = 0;    // reuse as local cursor
    }
    __syncthreads();
#pragma unroll
    for (int j = 0; j < EPT; j++) {
        if (c[j] >= 0) {
            int b = c[j] >> SBSH;
            int pos = base[b] + atomicAdd(&hist[b], 1);
            if (pos < CAP1)
                ebuf1[(size_t)b * CAP1 + pos] =
                    ((unsigned int)r[j] << SBSH) | (unsigned int)(c[j] & 1023);
        }
    }
}

// ---- Pass 2: one 1024-thread block per super-bucket. LDS 1024-bin histogram,
// wave-shuffle scan over PADDED (x4) degrees, scatter into the bucket's
// L2-resident window, pads -> dummy index n. Fused u0/out init. ----
__global__ void __launch_bounds__(1024)
k_sub(const int* __restrict__ bcursor, const unsigned int* __restrict__ ebuf1,
      unsigned int* __restrict__ csr, int2* __restrict__ rs_re,
      float2* __restrict__ nrm, const float* __restrict__ zarr,
      const float* __restrict__ temp, const float* __restrict__ bfc,
      float* __restrict__ u0, float* __restrict__ u1,
      float* __restrict__ out, int n) {
    __shared__ int hist[1024];
    __shared__ int wsum[16];
    int b = blockIdx.x;
    int t = threadIdx.x;
    int lane = t & 63;
    int w = t >> 6;

    hist[t] = 0;
    __syncthreads();
    int cnt = min(bcursor[b], CAP1);
    size_t g = (size_t)b * CAP1;
    int last = cnt > 0 ? cnt - 1 : 0;
    for (int j = t; j < cnt; j += 4096) {
        int j1 = j + 1024, j2 = j + 2048, j3 = j + 3072;
        unsigned int p0 = ebuf1[g + j];
        unsigned int p1 = ebuf1[g + min(j1, last)];
        unsigned int p2 = ebuf1[g + min(j2, last)];
        unsigned int p3 = ebuf1[g + min(j3, last)];
        atomicAdd(&hist[p0 & 1023], 1);
        if (j1 < cnt) atomicAdd(&hist[p1 & 1023], 1);
        if (j2 < cnt) atomicAdd(&hist[p2 & 1023], 1);
        if (j3 < cnt) atomicAdd(&hist[p3 & 1023], 1);
    }
    __syncthreads();

    int deg = hist[t];
    int pdeg = (deg + 3) & ~3;          // padded to multiple of 4 (16B uint4)
    int v = pdeg;
#pragma unroll
    for (int o = 1; o < 64; o <<= 1) {
        int u = __shfl_up(v, o);
        if (lane >= o) v += u;
    }
    if (lane == 63) wsum[w] = v;
    __syncthreads();
    if (w == 0) {
        int sv = (lane < 16) ? wsum[lane] : 0;
#pragma unroll
        for (int o = 1; o < 16; o <<= 1) {
            int u = __shfl_up(sv, o);
            if (lane >= o) sv += u;
        }
        if (lane < 16) wsum[lane] = sv;
    }
    __syncthreads();
    int pexcl = v - pdeg + (w > 0 ? wsum[w - 1] : 0);

    int node = (b << SBSH) + t;
    if (node < n) {
        int bs = (int)g + pexcl;
        rs_re[node] = make_int2(bs, bs + pdeg);
        float d = (float)(deg + 1);     // +1 self-loop
        float di = rsqrtf(d);
        nrm[node] = make_float2(di * di, d * di);   // {dinv2, sqrt(d)}
        float z = zarr[node];
        u0[node] = di * z;
        out[node] = fmaf(temp[0], z, bfc[0]);
    }
    if (b == 0 && t == 0) { u0[n] = 0.f; u1[n] = 0.f; }   // dummy gather slot
    __syncthreads();
    hist[t] = pexcl;                     // per-sub cursor
    __syncthreads();
    for (int j = t; j < cnt; j += 4096) {
        int j1 = j + 1024, j2 = j + 2048, j3 = j + 3072;
        unsigned int p0 = ebuf1[g + j];
        unsigned int p1 = ebuf1[g + min(j1, last)];
        unsigned int p2 = ebuf1[g + min(j2, last)];
        unsigned int p3 = ebuf1[g + min(j3, last)];
        int pos0 = atomicAdd(&hist[p0 & 1023], 1);
        csr[g + pos0] = p0 >> SBSH;
        if (j1 < cnt) { int p = atomicAdd(&hist[p1 & 1023], 1); csr[g + p] = p1 >> SBSH; }
        if (j2 < cnt) { int p = atomicAdd(&hist[p2 & 1023], 1); csr[g + p] = p2 >> SBSH; }
        if (j3 < cnt) { int p = atomicAdd(&hist[p3 & 1023], 1); csr[g + p] = p3 >> SBSH; }
    }
    __syncthreads();
    // pad fill: entries [pexcl+deg, pexcl+pdeg) -> dummy index n
    for (int p = pexcl + deg; p < pexcl + pdeg; p++)
        csr[g + p] = (unsigned int)n;
}

// ---- Hop k: 4 threads/node. Nontemporal uint4 index loads (csr has zero
// reuse -- keep u L2-resident), 4 independent gathers each. ----
__global__ void k_hop(const int2* __restrict__ rs_re, const v4u* __restrict__ csr4,
                      const float2* __restrict__ nrm,
                      const float* __restrict__ uprev, float* __restrict__ ucur,
                      float* __restrict__ out, const float* __restrict__ temp,
                      int k, int n, int is_last) {
    int tid = blockIdx.x * blockDim.x + threadIdx.x;
    int node = tid >> 2;
    int sub = tid & 3;
    if (node >= n) return;
    int2 se = rs_re[node];
    int s4 = se.x >> 2;                  // uint4 index of segment start
    int e4 = se.y >> 2;
    float sum = (sub == 0) ? uprev[node] : 0.f;   // self-loop term
    for (int i4 = s4 + sub; i4 < e4; i4 += 4) {
        v4u a = __builtin_nontemporal_load(&csr4[i4]);
        float v0 = uprev[a.x];
        float v1 = uprev[a.y];
        float v2 = uprev[a.z];
        float v3 = uprev[a.w];
        sum += (v0 + v1) + (v2 + v3);
    }
    sum += __shfl_xor(sum, 1);
    sum += __shfl_xor(sum, 2);
    if (sub == 0) {
        float2 nv = nrm[node];           // {dinv2, sqrt(d)}
        float u = nv.x * sum;
        if (!is_last) ucur[node] = u;
        out[node] = fmaf(temp[k] * nv.y, u, out[node]);
    }
}

static inline size_t align256(size_t v) { return (v + 255) & ~(size_t)255; }

extern "C" void kernel_launch(void* const* d_in, const int* in_sizes, int n_in,
                              void* d_out, int out_size, void* d_ws, size_t ws_size,
                              hipStream_t stream) {
    const float* x    = (const float*)d_in[0];
    const int*   ei   = (const int*)d_in[1];
    const float* W1   = (const float*)d_in[2];
    const float* b1   = (const float*)d_in[3];
    const float* W2   = (const float*)d_in[4];
    const float* b2   = (const float*)d_in[5];
    const float* temp = (const float*)d_in[6];
    const float* Wfc  = (const float*)d_in[7];
    const float* bfc  = (const float*)d_in[8];

    const int n = in_sizes[0];        // 100000 nodes
    const int e = in_sizes[1] / 2;    // 3.2M edges
    const int K = in_sizes[6] - 1;    // 10 hops
    const int nsb = (n + (1 << SBSH) - 1) >> SBSH;   // 98 super-buckets

    const int* erow = ei;             // edge_index[0] = source
    const int* ecol = ei + e;         // edge_index[1] = target

    float* out = (float*)d_out;

    // workspace carve
    char* ws = (char*)d_ws;
    int*          bcursor = (int*)ws;          ws += align256((size_t)128 * 4);
    unsigned int* ebuf1   = (unsigned int*)ws; ws += align256((size_t)nsb * CAP1 * 4);
    unsigned int* csr     = (unsigned int*)ws; ws += align256((size_t)nsb * CAP1 * 4);
    int2*         rs_re   = (int2*)ws;         ws += align256((size_t)n * 8);
    float2*       nrm     = (float2*)ws;       ws += align256((size_t)n * 8);
    float*        zarr    = (float*)ws;        ws += align256((size_t)(n + 1) * 4);
    float*        u0      = (float*)ws;        ws += align256((size_t)(n + 1) * 4);
    float*        u1      = (float*)ws;        ws += align256((size_t)(n + 1) * 4);

    const int gM = (n + TPB - 1) / TPB;          // 391 MLP blocks
    const int gS = (e + CH - 1) / CH;            // 782 scatter blocks
    const int gH = (4 * n + TPB - 1) / TPB;      // 4 threads/node hops

    k_mlp<<<gM, TPB, 0, stream>>>(x, W1, b1, W2, b2, Wfc, zarr, bcursor, n);
    k_scatter<<<gS, TSC, 0, stream>>>(erow, ecol, bcursor, ebuf1, e, nsb);
    k_sub<<<nsb, 1024, 0, stream>>>(bcursor, ebuf1, csr, rs_re, nrm,
                                    zarr, temp, bfc, u0, u1, out, n);

    float* uin = u0;
    float* uout = u1;
    for (int k = 1; k <= K; k++) {
        k_hop<<<gH, TPB, 0, stream>>>(rs_re, (const v4u*)csr, nrm, uin, uout,
                                      out, temp, k, n, (k == K) ? 1 : 0);
        float* t2 = uin; uin = uout; uout = t2;
    }
}

// Round 15
// 332.432 us; speedup vs baseline: 1.9327x; 1.0742x over previous
//
#include <hip/hip_runtime.h>

// GPR-GNN: out = b_fc + sum_k temp[k] * A_hat^k (MLP(x) @ W_fc)
// == Best-known configuration (R11, 332us) — consolidation revert ==
// Trick 1: project features to scalar BEFORE propagation (linearity) -> 1 float/node.
// Trick 2: per-edge GLOBAL atomics cost ~35B memory-side RMW (measured R2/R3)
//          -> per-edge atomics are LDS-only.
// Trick 3: u-space propagation u_k = D^{-1/2} z_k -> per-edge work is one
//          unweighted gather+add; CSR is row indices only.
// Trick 4: CSR build = two-level counting sort (98 super-buckets of 1024 nodes;
//          pass-1 runs ~600B >> 128B line -> write amp ~1; pass-2 in an
//          L2-resident window). Scatter: 512 thr x 8 edges.
// Trick 5: segments padded to x4; pads index dummy slot n (u[n]=0) -> hop does
//          ONE aligned uint4 index load + 4 independent gathers per thread.
// MEASURED FLOOR (R7/R9/R10/R12/R13/R14): gather hop ~20us = scattered-request
//          rate bound (3.3M divergent 4B loads, ~1 L2 transaction each).
//          Insensitive to: index ILP (R7/R9), LDS tiling (R10: serial-phase
//          cliff; R13: staging overhead), nontemporal csr (R14), thread/node
//          ratio 4 (R14 regressed vs 8).
// ANTI-LESSON (R8): cooperative grid.sync ~125us each on 8-XCD MI355X.
// ANTI-LESSON (R12): in-kernel ACQ_REL agent atomics ~us each. Kernel
//          boundaries are the only cheap device-wide sync.
// ANTI-LESSON (R9): MLP fused into scatter adds ~20us serial wave chains.

#define TPB  256
#define TSC  512             // scatter block threads
#define SBSH 10              // 1024 nodes per super-bucket
#define CAP1 37376           // capacity (mean padded ~34200, ~16 sigma; mult of 4)
#define EPT  8               // edges per thread in pass 1
#define CH   (TSC * EPT)     // 4096 edges per scatter block

// ---- MLP (thread per node, register-blocked) + bcursor zeroing ----
__global__ void k_mlp(const float* __restrict__ x, const float* __restrict__ W1,
                      const float* __restrict__ b1, const float* __restrict__ W2,
                      const float* __restrict__ b2, const float* __restrict__ Wfc,
                      float* __restrict__ zarr, int* __restrict__ bcursor, int n) {
    int i = blockIdx.x * blockDim.x + threadIdx.x;
    if (i < 128) bcursor[i] = 0;
    if (i >= n) return;
    float xv = x[i];
    float h1[32];
#pragma unroll
    for (int j = 0; j < 32; j++)
        h1[j] = fmaxf(fmaf(xv, W1[j], b1[j]), 0.f);
    float z = 0.f;
#pragma unroll
    for (int fc = 0; fc < 4; fc++) {
        float acc[16];
#pragma unroll
        for (int f = 0; f < 16; f++) acc[f] = b2[fc * 16 + f];
#pragma unroll
        for (int j = 0; j < 32; j++) {
            float h = h1[j];
#pragma unroll
            for (int f = 0; f < 16; f++)
                acc[f] = fmaf(h, W2[j * 64 + fc * 16 + f], acc[f]);
        }
#pragma unroll
        for (int f = 0; f < 16; f++)
            z = fmaf(fmaxf(acc[f], 0.f), Wfc[fc * 16 + f], z);
    }
    zarr[i] = z;
}

// ---- Pass 1: bucket edges into 98 super-buckets, packed (row<<10)|tgt10 ----
__global__ void __launch_bounds__(TSC)
k_scatter(const int* __restrict__ erow, const int* __restrict__ ecol,
          int* __restrict__ bcursor, unsigned int* __restrict__ ebuf1,
          int e, int nsb) {
    __shared__ int hist[128];
    __shared__ int base[128];
    int t = threadIdx.x;
    int s = blockIdx.x * CH;
    int r[EPT], c[EPT];

    if (t < 128) hist[t] = 0;
    __syncthreads();
#pragma unroll
    for (int j = 0; j < EPT; j++) {
        int i = s + j * TSC + t;
        bool ok = (i < e);
        c[j] = ok ? ecol[i] : -1;
        r[j] = ok ? erow[i] : 0;
        if (ok) atomicAdd(&hist[c[j] >> SBSH], 1);
    }
    __syncthreads();
    if (t < nsb) {
        int cc = hist[t];
        base[t] = cc ? atomicAdd(&bcursor[t], cc) : 0;
        hist[t] = 0;    // reuse as local cursor
    }
    __syncthreads();
#pragma unroll
    for (int j = 0; j < EPT; j++) {
        if (c[j] >= 0) {
            int b = c[j] >> SBSH;
            int pos = base[b] + atomicAdd(&hist[b], 1);
            if (pos < CAP1)
                ebuf1[(size_t)b * CAP1 + pos] =
                    ((unsigned int)r[j] << SBSH) | (unsigned int)(c[j] & 1023);
        }
    }
}

// ---- Pass 2: one 1024-thread block per super-bucket. LDS 1024-bin histogram,
// wave-shuffle scan over PADDED (x4) degrees, scatter into the bucket's
// L2-resident window, pads -> dummy index n. Fused u0/out init. ----
__global__ void __launch_bounds__(1024)
k_sub(const int* __restrict__ bcursor, const unsigned int* __restrict__ ebuf1,
      unsigned int* __restrict__ csr, int2* __restrict__ rs_re,
      float2* __restrict__ nrm, const float* __restrict__ zarr,
      const float* __restrict__ temp, const float* __restrict__ bfc,
      float* __restrict__ u0, float* __restrict__ u1,
      float* __restrict__ out, int n) {
    __shared__ int hist[1024];
    __shared__ int wsum[16];
    int b = blockIdx.x;
    int t = threadIdx.x;
    int lane = t & 63;
    int w = t >> 6;

    hist[t] = 0;
    __syncthreads();
    int cnt = min(bcursor[b], CAP1);
    size_t g = (size_t)b * CAP1;
    int last = cnt > 0 ? cnt - 1 : 0;
    for (int j = t; j < cnt; j += 4096) {
        int j1 = j + 1024, j2 = j + 2048, j3 = j + 3072;
        unsigned int p0 = ebuf1[g + j];
        unsigned int p1 = ebuf1[g + min(j1, last)];
        unsigned int p2 = ebuf1[g + min(j2, last)];
        unsigned int p3 = ebuf1[g + min(j3, last)];
        atomicAdd(&hist[p0 & 1023], 1);
        if (j1 < cnt) atomicAdd(&hist[p1 & 1023], 1);
        if (j2 < cnt) atomicAdd(&hist[p2 & 1023], 1);
        if (j3 < cnt) atomicAdd(&hist[p3 & 1023], 1);
    }
    __syncthreads();

    int deg = hist[t];
    int pdeg = (deg + 3) & ~3;          // padded to multiple of 4 (16B uint4)
    int v = pdeg;
#pragma unroll
    for (int o = 1; o < 64; o <<= 1) {
        int u = __shfl_up(v, o);
        if (lane >= o) v += u;
    }
    if (lane == 63) wsum[w] = v;
    __syncthreads();
    if (w == 0) {
        int sv = (lane < 16) ? wsum[lane] : 0;
#pragma unroll
        for (int o = 1; o < 16; o <<= 1) {
            int u = __shfl_up(sv, o);
            if (lane >= o) sv += u;
        }
        if (lane < 16) wsum[lane] = sv;
    }
    __syncthreads();
    int pexcl = v - pdeg + (w > 0 ? wsum[w - 1] : 0);

    int node = (b << SBSH) + t;
    if (node < n) {
        int bs = (int)g + pexcl;
        rs_re[node] = make_int2(bs, bs + pdeg);
        float d = (float)(deg + 1);     // +1 self-loop
        float di = rsqrtf(d);
        nrm[node] = make_float2(di * di, d * di);   // {dinv2, sqrt(d)}
        float z = zarr[node];
        u0[node] = di * z;
        out[node] = fmaf(temp[0], z, bfc[0]);
    }
    if (b == 0 && t == 0) { u0[n] = 0.f; u1[n] = 0.f; }   // dummy gather slot
    __syncthreads();
    hist[t] = pexcl;                     // per-sub cursor
    __syncthreads();
    for (int j = t; j < cnt; j += 4096) {
        int j1 = j + 1024, j2 = j + 2048, j3 = j + 3072;
        unsigned int p0 = ebuf1[g + j];
        unsigned int p1 = ebuf1[g + min(j1, last)];
        unsigned int p2 = ebuf1[g + min(j2, last)];
        unsigned int p3 = ebuf1[g + min(j3, last)];
        int pos0 = atomicAdd(&hist[p0 & 1023], 1);
        csr[g + pos0] = p0 >> SBSH;
        if (j1 < cnt) { int p = atomicAdd(&hist[p1 & 1023], 1); csr[g + p] = p1 >> SBSH; }
        if (j2 < cnt) { int p = atomicAdd(&hist[p2 & 1023], 1); csr[g + p] = p2 >> SBSH; }
        if (j3 < cnt) { int p = atomicAdd(&hist[p3 & 1023], 1); csr[g + p] = p3 >> SBSH; }
    }
    __syncthreads();
    // pad fill: entries [pexcl+deg, pexcl+pdeg) -> dummy index n
    for (int p = pexcl + deg; p < pexcl + pdeg; p++)
        csr[g + p] = (unsigned int)n;
}

// ---- Hop k: 8 threads/node, one aligned uint4 index load + 4 independent
// gathers per thread. u_k = dinv2*(u_{k-1}+sum); out += temp[k]*sqrt(d)*u_k ----
__global__ void k_hop(const int2* __restrict__ rs_re, const uint4* __restrict__ csr4,
                      const float2* __restrict__ nrm,
                      const float* __restrict__ uprev, float* __restrict__ ucur,
                      float* __restrict__ out, const float* __restrict__ temp,
                      int k, int n, int is_last) {
    int tid = blockIdx.x * blockDim.x + threadIdx.x;
    int node = tid >> 3;
    int sub = tid & 7;
    if (node >= n) return;
    int2 se = rs_re[node];
    int s4 = se.x >> 2;                  // uint4 index of segment start
    int e4 = se.y >> 2;
    float sum = (sub == 0) ? uprev[node] : 0.f;   // self-loop term
    for (int i4 = s4 + sub; i4 < e4; i4 += 8) {
        uint4 a = csr4[i4];
        float v0 = uprev[a.x];
        float v1 = uprev[a.y];
        float v2 = uprev[a.z];
        float v3 = uprev[a.w];
        sum += (v0 + v1) + (v2 + v3);
    }
    sum += __shfl_xor(sum, 1);
    sum += __shfl_xor(sum, 2);
    sum += __shfl_xor(sum, 4);
    if (sub == 0) {
        float2 nv = nrm[node];           // {dinv2, sqrt(d)}
        float u = nv.x * sum;
        if (!is_last) ucur[node] = u;
        out[node] = fmaf(temp[k] * nv.y, u, out[node]);
    }
}

static inline size_t align256(size_t v) { return (v + 255) & ~(size_t)255; }

extern "C" void kernel_launch(void* const* d_in, const int* in_sizes, int n_in,
                              void* d_out, int out_size, void* d_ws, size_t ws_size,
                              hipStream_t stream) {
    const float* x    = (const float*)d_in[0];
    const int*   ei   = (const int*)d_in[1];
    const float* W1   = (const float*)d_in[2];
    const float* b1   = (const float*)d_in[3];
    const float* W2   = (const float*)d_in[4];
    const float* b2   = (const float*)d_in[5];
    const float* temp = (const float*)d_in[6];
    const float* Wfc  = (const float*)d_in[7];
    const float* bfc  = (const float*)d_in[8];

    const int n = in_sizes[0];        // 100000 nodes
    const int e = in_sizes[1] / 2;    // 3.2M edges
    const int K = in_sizes[6] - 1;    // 10 hops
    const int nsb = (n + (1 << SBSH) - 1) >> SBSH;   // 98 super-buckets

    const int* erow = ei;             // edge_index[0] = source
    const int* ecol = ei + e;         // edge_index[1] = target

    float* out = (float*)d_out;

    // workspace carve
    char* ws = (char*)d_ws;
    int*          bcursor = (int*)ws;          ws += align256((size_t)128 * 4);
    unsigned int* ebuf1   = (unsigned int*)ws; ws += align256((size_t)nsb * CAP1 * 4);
    unsigned int* csr     = (unsigned int*)ws; ws += align256((size_t)nsb * CAP1 * 4);
    int2*         rs_re   = (int2*)ws;         ws += align256((size_t)n * 8);
    float2*       nrm     = (float2*)ws;       ws += align256((size_t)n * 8);
    float*        zarr    = (float*)ws;        ws += align256((size_t)(n + 1) * 4);
    float*        u0      = (float*)ws;        ws += align256((size_t)(n + 1) * 4);
    float*        u1      = (float*)ws;        ws += align256((size_t)(n + 1) * 4);

    const int gM = (n + TPB - 1) / TPB;          // 391 MLP blocks
    const int gS = (e + CH - 1) / CH;            // 782 scatter blocks
    const int gH = (8 * n + TPB - 1) / TPB;      // 8 threads/node hops

    k_mlp<<<gM, TPB, 0, stream>>>(x, W1, b1, W2, b2, Wfc, zarr, bcursor, n);
    k_scatter<<<gS, TSC, 0, stream>>>(erow, ecol, bcursor, ebuf1, e, nsb);
    k_sub<<<nsb, 1024, 0, stream>>>(bcursor, ebuf1, csr, rs_re, nrm,
                                    zarr, temp, bfc, u0, u1, out, n);

    float* uin = u0;
    float* uout = u1;
    for (int k = 1; k <= K; k++) {
        k_hop<<<gH, TPB, 0, stream>>>(rs_re, (const uint4*)csr, nrm, uin, uout,
                                      out, temp, k, n, (k == K) ? 1 : 0);
        float* t2 = uin; uin = uout; uout = t2;
    }
}